// Round 4
// baseline (217.371 us; speedup 1.0000x reference)
//
#include <hip/hip_runtime.h>

#define D 128

typedef short s16x8 __attribute__((ext_vector_type(8)));
typedef float f32x4 __attribute__((ext_vector_type(4)));

static __device__ __forceinline__ float bf2f(ushort h) {
    return __uint_as_float(((uint)h) << 16);
}
static __device__ __forceinline__ ushort f2bf(float f) {
    uint u = __float_as_uint(f);
    u += 0x7fffu + ((u >> 16) & 1u);   // RNE
    return (ushort)(u >> 16);
}

// ---------------- prep: x->bf16  +  degree count  +  W pack ----------------
// W B-fragment layout (mfma_f32_16x16x32_bf16): lane l, elem i holds
// W[ks*32 + (l>>4)*8 + i][nf*16 + (l&15)], packed at ((ks*8+nf)*64+lane)*8+i.
__global__ void prep_kernel(const float4* __restrict__ x4, ushort4* __restrict__ xh4, int n4,
                            const int* __restrict__ dst, int* __restrict__ cnt, int E,
                            const float* __restrict__ W1, const float* __restrict__ W2,
                            ushort* __restrict__ wp) {
    int tid = blockIdx.x * blockDim.x + threadIdx.x;
    int stride = gridDim.x * blockDim.x;
    for (int i = tid; i < n4; i += stride) {
        float4 v = x4[i];
        ushort4 h;
        h.x = f2bf(v.x); h.y = f2bf(v.y); h.z = f2bf(v.z); h.w = f2bf(v.w);
        xh4[i] = h;
    }
    for (int e = tid; e < E; e += stride) atomicAdd(&cnt[dst[e]], 1);
    if (tid < 4096) {
        int m = tid >> 11;
        int r = tid & 2047;
        int lane = r & 63;
        int nf = (r >> 6) & 7;
        int ks = r >> 9;
        const float* W = m ? W2 : W1;
        ushort* o = wp + m * 16384;
        int k0 = ks * 32 + ((lane >> 4) << 3);
        int c = nf * 16 + (lane & 15);
        #pragma unroll
        for (int i = 0; i < 8; ++i) o[r * 8 + i] = f2bf(W[(k0 + i) * D + c]);
    }
}

// ---------------- CSR alloc + fill ----------------
__global__ void alloc_kernel(const int* __restrict__ cnt, int* __restrict__ start,
                             int* __restrict__ cur, int* __restrict__ total, int n) {
    int i = blockIdx.x * blockDim.x + threadIdx.x;
    int lane = threadIdx.x & 63;
    int c = (i < n) ? cnt[i] : 0;
    int inc = c;
    #pragma unroll
    for (int s = 1; s < 64; s <<= 1) {
        int u = __shfl_up(inc, (unsigned)s);
        if (lane >= s) inc += u;
    }
    int base = 0;
    if (lane == 63) base = atomicAdd(total, inc);
    base = __shfl(base, 63);
    if (i < n) { int st = base + inc - c; start[i] = st; cur[i] = st; }
}

__global__ void fill_kernel(const int* __restrict__ src, const int* __restrict__ dst,
                            int* __restrict__ cur, int* __restrict__ bucket, int E) {
    int e = blockIdx.x * blockDim.x + threadIdx.x;
    if (e < E) {
        int p = atomicAdd(&cur[dst[e]], 1);
        bucket[p] = src[e];
    }
}

// ---------------- mega: gather -> GEMM1(relu) -> GEMM2 -> out + stats ----------------
// One 16-row tile per wave per iteration. Per-wave LDS tile buffer (4KB),
// XOR-swizzled (byte ^= (row&7)<<4) so 16-lane row-sliced ds_read_b128 is
// conflict-free. Per-wave DS ops are in-order -> no barriers inside the loop.
__global__ __launch_bounds__(256, 2)
void mega_kernel(const ushort4* __restrict__ xh4, const float4* __restrict__ x4,
                 const int* __restrict__ start, const int* __restrict__ cnt,
                 const int* __restrict__ bucket, const ushort* __restrict__ wp,
                 const float* __restrict__ b1, const float* __restrict__ b2,
                 float* __restrict__ out, float* __restrict__ stats, int nTiles) {
    __shared__ ushort W1s[16384];   // 32 KB
    __shared__ ushort W2s[16384];   // 32 KB
    __shared__ ushort tileb[4][2048]; // 4 KB per wave
    {
        const float4* g = (const float4*)wp;
        float4* l1 = (float4*)W1s;
        float4* l2 = (float4*)W2s;
        for (int i = threadIdx.x; i < 2048; i += 256) { l1[i] = g[i]; l2[i] = g[2048 + i]; }
    }
    __syncthreads();

    int wave = threadIdx.x >> 6, lane = threadIdx.x & 63;
    int rsel = lane & 15;      // A-row / C-col selector
    int csel = lane >> 4;      // k-chunk / C-row-group selector
    int half = lane >> 5, l31 = lane & 31;
    char* tb = (char*)tileb[wave];

    float b1v[8], b2v[8];
    #pragma unroll
    for (int nf = 0; nf < 8; ++nf) { b1v[nf] = b1[nf * 16 + rsel]; b2v[nf] = b2[nf * 16 + rsel]; }
    float ssum[8], ssq[8];
    #pragma unroll
    for (int nf = 0; nf < 8; ++nf) { ssum[nf] = 0.f; ssq[nf] = 0.f; }

    for (int tile = blockIdx.x * 4 + wave; tile < nTiles; tile += gridDim.x * 4) {
        int row0 = tile * 16;
        // ---- gather: half-wave per node, rows {2p+half} ----
        #pragma unroll 1
        for (int p = 0; p < 8; ++p) {
            int r = p * 2 + half;
            int node = row0 + r;
            int e0 = start[node];
            int eend = e0 + cnt[node];
            float a0 = 0.f, a1 = 0.f, a2 = 0.f, a3 = 0.f;
            int e = e0;
            for (; e + 4 <= eend; e += 4) {
                int s0 = bucket[e], s1 = bucket[e + 1], s2 = bucket[e + 2], s3 = bucket[e + 3];
                ushort4 v0 = xh4[(size_t)s0 * 32 + l31];
                ushort4 v1 = xh4[(size_t)s1 * 32 + l31];
                ushort4 v2 = xh4[(size_t)s2 * 32 + l31];
                ushort4 v3 = xh4[(size_t)s3 * 32 + l31];
                a0 += bf2f(v0.x) + bf2f(v1.x) + bf2f(v2.x) + bf2f(v3.x);
                a1 += bf2f(v0.y) + bf2f(v1.y) + bf2f(v2.y) + bf2f(v3.y);
                a2 += bf2f(v0.z) + bf2f(v1.z) + bf2f(v2.z) + bf2f(v3.z);
                a3 += bf2f(v0.w) + bf2f(v1.w) + bf2f(v2.w) + bf2f(v3.w);
            }
            for (; e < eend; ++e) {
                int s = bucket[e];
                ushort4 v = xh4[(size_t)s * 32 + l31];
                a0 += bf2f(v.x); a1 += bf2f(v.y); a2 += bf2f(v.z); a3 += bf2f(v.w);
            }
            float4 xv = x4[(size_t)node * 32 + l31];
            ushort4 zo;
            zo.x = f2bf(a0 + xv.x); zo.y = f2bf(a1 + xv.y);
            zo.z = f2bf(a2 + xv.z); zo.w = f2bf(a3 + xv.w);
            *(ushort4*)(tb + r * 256 + ((l31 * 8) ^ ((r & 7) << 4))) = zo;
        }
        // ---- GEMM1: acc = z @ W1 ----
        f32x4 acc[8];
        #pragma unroll
        for (int nf = 0; nf < 8; ++nf) acc[nf] = (f32x4){0.f, 0.f, 0.f, 0.f};
        #pragma unroll
        for (int ks = 0; ks < 4; ++ks) {
            s16x8 a = *(const s16x8*)(tb + rsel * 256 + ((ks * 64 + csel * 16) ^ ((rsel & 7) << 4)));
            #pragma unroll
            for (int nf = 0; nf < 8; ++nf) {
                s16x8 b = *(const s16x8*)(&W1s[((ks * 8 + nf) * 64 + lane) * 8]);
                acc[nf] = __builtin_amdgcn_mfma_f32_16x16x32_bf16(a, b, acc[nf], 0, 0, 0);
            }
        }
        // ---- h1 = relu(acc + b1) -> same LDS buffer (per-wave DS in-order) ----
        #pragma unroll
        for (int nf = 0; nf < 8; ++nf) {
            int col2 = (nf * 16 + rsel) * 2;
            #pragma unroll
            for (int r4 = 0; r4 < 4; ++r4) {
                int rr = csel * 4 + r4;
                float v = fmaxf(acc[nf][r4] + b1v[nf], 0.f);
                *(ushort*)(tb + rr * 256 + (col2 ^ ((rr & 7) << 4))) = f2bf(v);
            }
        }
        // ---- GEMM2: acc = h1 @ W2 ----
        #pragma unroll
        for (int nf = 0; nf < 8; ++nf) acc[nf] = (f32x4){0.f, 0.f, 0.f, 0.f};
        #pragma unroll
        for (int ks = 0; ks < 4; ++ks) {
            s16x8 a = *(const s16x8*)(tb + rsel * 256 + ((ks * 64 + csel * 16) ^ ((rsel & 7) << 4)));
            #pragma unroll
            for (int nf = 0; nf < 8; ++nf) {
                s16x8 b = *(const s16x8*)(&W2s[((ks * 8 + nf) * 64 + lane) * 8]);
                acc[nf] = __builtin_amdgcn_mfma_f32_16x16x32_bf16(a, b, acc[nf], 0, 0, 0);
            }
        }
        // ---- out = acc + b2 (fp32), stats in regs ----
        #pragma unroll
        for (int nf = 0; nf < 8; ++nf) {
            int col = nf * 16 + rsel;
            #pragma unroll
            for (int r4 = 0; r4 < 4; ++r4) {
                float v = acc[nf][r4] + b2v[nf];
                out[(size_t)(row0 + csel * 4 + r4) * D + col] = v;
                ssum[nf] += v; ssq[nf] += v * v;
            }
        }
    }
    // ---- flush stats: reduce over csel groups, one atomic per (col, block-wave) ----
    #pragma unroll
    for (int nf = 0; nf < 8; ++nf) {
        float s = ssum[nf], q = ssq[nf];
        s += __shfl_xor(s, 16); s += __shfl_xor(s, 32);
        q += __shfl_xor(q, 16); q += __shfl_xor(q, 32);
        if (csel == 0) {
            atomicAdd(&stats[nf * 16 + rsel], s);
            atomicAdd(&stats[128 + nf * 16 + rsel], q);
        }
    }
}

// ---------------- BN normalize + residual ----------------
__global__ void bn_final(float4* __restrict__ out4, const float4* __restrict__ x4,
                         const float* __restrict__ stats, const float* __restrict__ gamma,
                         const float* __restrict__ beta, int n4, float invN) {
    int i = blockIdx.x * blockDim.x + threadIdx.x;
    if (i >= n4) return;
    int cc = i & 31;
    const float4* s4 = (const float4*)stats;
    float4 sum = s4[cc], sq = s4[32 + cc];
    float4 g = ((const float4*)gamma)[cc], b = ((const float4*)beta)[cc];
    float4 h = out4[i], xx = x4[i];
    float4 o;
    {
        float m = sum.x * invN, v = sq.x * invN - m * m, iv = rsqrtf(v + 1e-5f);
        o.x = (h.x - m) * iv * g.x + b.x + xx.x;
    }
    {
        float m = sum.y * invN, v = sq.y * invN - m * m, iv = rsqrtf(v + 1e-5f);
        o.y = (h.y - m) * iv * g.y + b.y + xx.y;
    }
    {
        float m = sum.z * invN, v = sq.z * invN - m * m, iv = rsqrtf(v + 1e-5f);
        o.z = (h.z - m) * iv * g.z + b.z + xx.z;
    }
    {
        float m = sum.w * invN, v = sq.w * invN - m * m, iv = rsqrtf(v + 1e-5f);
        o.w = (h.w - m) * iv * g.w + b.w + xx.w;
    }
    out4[i] = o;
}

extern "C" void kernel_launch(void* const* d_in, const int* in_sizes, int n_in,
                              void* d_out, int out_size, void* d_ws, size_t ws_size,
                              hipStream_t stream) {
    const float* x     = (const float*)d_in[0];
    const int*   ei    = (const int*)d_in[1];
    const float* W1    = (const float*)d_in[2];
    const float* b1    = (const float*)d_in[3];
    const float* W2    = (const float*)d_in[4];
    const float* b2    = (const float*)d_in[5];
    const float* gamma = (const float*)d_in[6];
    const float* beta  = (const float*)d_in[7];
    float* out = (float*)d_out;

    int N = in_sizes[0] / D;   // 50000
    int E = in_sizes[1] / 2;   // 600000
    const int* src = ei;
    const int* dst = ei + E;

    size_t NB = (size_t)N * D;
    ushort* xh   = (ushort*)d_ws;          // NB ushorts
    ushort* wp   = xh + NB;                // 2*16384
    float*  stats = (float*)(wp + 32768);  // 256 floats (16B aligned)
    int*    cnt  = (int*)(stats + 256);    // N
    int*    tot  = cnt + N;                // 1
    int*    startA = tot + 1;              // N
    int*    cur  = startA + N;             // N
    int*    bucket = cur + N;              // E

    hipMemsetAsync(stats, 0, (size_t)(256 + N + 1) * sizeof(int), stream);

    const int B = 256;
    int n4 = (int)(NB / 4);
    prep_kernel<<<2048, B, 0, stream>>>((const float4*)x, (ushort4*)xh, n4,
                                        dst, cnt, E, W1, W2, wp);
    alloc_kernel<<<(N + B - 1) / B, B, 0, stream>>>(cnt, startA, cur, tot, N);
    fill_kernel<<<(E + B - 1) / B, B, 0, stream>>>(src, dst, cur, bucket, E);
    int nTiles = (N + 15) / 16;   // 3125
    mega_kernel<<<391, B, 0, stream>>>((const ushort4*)xh, (const float4*)x,
                                       startA, cnt, bucket, wp, b1, b2,
                                       out, stats, nTiles);
    bn_final<<<(n4 + B - 1) / B, B, 0, stream>>>((float4*)out, (const float4*)x, stats,
                                                 gamma, beta, n4, 1.0f / (float)N);
}

// Round 5
// 191.856 us; speedup vs baseline: 1.1330x; 1.1330x over previous
//
#include <hip/hip_runtime.h>

#define D 128

typedef short s16x8 __attribute__((ext_vector_type(8)));
typedef float f32x4 __attribute__((ext_vector_type(4)));

static __device__ __forceinline__ float bf2f(ushort h) {
    return __uint_as_float(((uint)h) << 16);
}
static __device__ __forceinline__ ushort f2bf(float f) {
    uint u = __float_as_uint(f);
    u += 0x7fffu + ((u >> 16) & 1u);   // RNE
    return (ushort)(u >> 16);
}

// ---------------- prep: x->bf16  +  degree count  +  W pack ----------------
// W B-fragment layout (mfma_f32_16x16x32_bf16): lane l, elem i holds
// W[ks*32 + (l>>4)*8 + i][nf*16 + (l&15)], packed at ((ks*8+nf)*64+lane)*8+i.
__global__ void prep_kernel(const float4* __restrict__ x4, ushort4* __restrict__ xh4, int n4,
                            const int* __restrict__ dst, int* __restrict__ cnt, int E,
                            const float* __restrict__ W1, const float* __restrict__ W2,
                            ushort* __restrict__ wp) {
    int tid = blockIdx.x * blockDim.x + threadIdx.x;
    int stride = gridDim.x * blockDim.x;
    for (int i = tid; i < n4; i += stride) {
        float4 v = x4[i];
        ushort4 h;
        h.x = f2bf(v.x); h.y = f2bf(v.y); h.z = f2bf(v.z); h.w = f2bf(v.w);
        xh4[i] = h;
    }
    for (int e = tid; e < E; e += stride) atomicAdd(&cnt[dst[e]], 1);
    if (tid < 4096) {
        int m = tid >> 11;
        int r = tid & 2047;
        int lane = r & 63;
        int nf = (r >> 6) & 7;
        int ks = r >> 9;
        const float* W = m ? W2 : W1;
        ushort* o = wp + m * 16384;
        int k0 = ks * 32 + ((lane >> 4) << 3);
        int c = nf * 16 + (lane & 15);
        #pragma unroll
        for (int i = 0; i < 8; ++i) o[r * 8 + i] = f2bf(W[(k0 + i) * D + c]);
    }
}

// ---------------- CSR alloc + fill ----------------
__global__ void alloc_kernel(const int* __restrict__ cnt, int* __restrict__ start,
                             int* __restrict__ cur, int* __restrict__ total, int n) {
    int i = blockIdx.x * blockDim.x + threadIdx.x;
    int lane = threadIdx.x & 63;
    int c = (i < n) ? cnt[i] : 0;
    int inc = c;
    #pragma unroll
    for (int s = 1; s < 64; s <<= 1) {
        int u = __shfl_up(inc, (unsigned)s);
        if (lane >= s) inc += u;
    }
    int base = 0;
    if (lane == 63) base = atomicAdd(total, inc);
    base = __shfl(base, 63);
    if (i < n) { int st = base + inc - c; start[i] = st; cur[i] = st; }
}

__global__ void fill_kernel(const int* __restrict__ src, const int* __restrict__ dst,
                            int* __restrict__ cur, int* __restrict__ bucket, int E) {
    int e = blockIdx.x * blockDim.x + threadIdx.x;
    if (e < E) {
        int p = atomicAdd(&cur[dst[e]], 1);
        bucket[p] = src[e];
    }
}

// ---------------- gather: z = xh + segment_sum(xh[src]) -> bf16 ----------------
// half-wave (32 lanes, 8B/lane) per node; 8-deep unroll for MLP. Latency-bound:
// runs standalone at high occupancy (fusing this into the MFMA kernel cost 2x in R4).
__global__ void gather_kernel(const ushort4* __restrict__ xh4,
                              const int* __restrict__ start, const int* __restrict__ cnt,
                              const int* __restrict__ bucket,
                              ushort4* __restrict__ z4, int n) {
    int node = blockIdx.x * 8 + (threadIdx.x >> 5);
    int lane = threadIdx.x & 31;
    if (node >= n) return;
    int e0 = start[node];
    int eend = e0 + cnt[node];
    float a0 = 0.f, a1 = 0.f, a2 = 0.f, a3 = 0.f;
    int e = e0;
    for (; e + 8 <= eend; e += 8) {
        int s0 = bucket[e],     s1 = bucket[e + 1], s2 = bucket[e + 2], s3 = bucket[e + 3];
        int s4 = bucket[e + 4], s5 = bucket[e + 5], s6 = bucket[e + 6], s7 = bucket[e + 7];
        ushort4 v0 = xh4[(size_t)s0 * 32 + lane];
        ushort4 v1 = xh4[(size_t)s1 * 32 + lane];
        ushort4 v2 = xh4[(size_t)s2 * 32 + lane];
        ushort4 v3 = xh4[(size_t)s3 * 32 + lane];
        ushort4 v4 = xh4[(size_t)s4 * 32 + lane];
        ushort4 v5 = xh4[(size_t)s5 * 32 + lane];
        ushort4 v6 = xh4[(size_t)s6 * 32 + lane];
        ushort4 v7 = xh4[(size_t)s7 * 32 + lane];
        a0 += bf2f(v0.x) + bf2f(v1.x) + bf2f(v2.x) + bf2f(v3.x)
            + bf2f(v4.x) + bf2f(v5.x) + bf2f(v6.x) + bf2f(v7.x);
        a1 += bf2f(v0.y) + bf2f(v1.y) + bf2f(v2.y) + bf2f(v3.y)
            + bf2f(v4.y) + bf2f(v5.y) + bf2f(v6.y) + bf2f(v7.y);
        a2 += bf2f(v0.z) + bf2f(v1.z) + bf2f(v2.z) + bf2f(v3.z)
            + bf2f(v4.z) + bf2f(v5.z) + bf2f(v6.z) + bf2f(v7.z);
        a3 += bf2f(v0.w) + bf2f(v1.w) + bf2f(v2.w) + bf2f(v3.w)
            + bf2f(v4.w) + bf2f(v5.w) + bf2f(v6.w) + bf2f(v7.w);
    }
    for (; e + 4 <= eend; e += 4) {
        int s0 = bucket[e], s1 = bucket[e + 1], s2 = bucket[e + 2], s3 = bucket[e + 3];
        ushort4 v0 = xh4[(size_t)s0 * 32 + lane];
        ushort4 v1 = xh4[(size_t)s1 * 32 + lane];
        ushort4 v2 = xh4[(size_t)s2 * 32 + lane];
        ushort4 v3 = xh4[(size_t)s3 * 32 + lane];
        a0 += bf2f(v0.x) + bf2f(v1.x) + bf2f(v2.x) + bf2f(v3.x);
        a1 += bf2f(v0.y) + bf2f(v1.y) + bf2f(v2.y) + bf2f(v3.y);
        a2 += bf2f(v0.z) + bf2f(v1.z) + bf2f(v2.z) + bf2f(v3.z);
        a3 += bf2f(v0.w) + bf2f(v1.w) + bf2f(v2.w) + bf2f(v3.w);
    }
    for (; e < eend; ++e) {
        int s = bucket[e];
        ushort4 v = xh4[(size_t)s * 32 + lane];
        a0 += bf2f(v.x); a1 += bf2f(v.y); a2 += bf2f(v.z); a3 += bf2f(v.w);
    }
    ushort4 xv = xh4[(size_t)node * 32 + lane];   // bf16 self-term
    ushort4 zo;
    zo.x = f2bf(a0 + bf2f(xv.x)); zo.y = f2bf(a1 + bf2f(xv.y));
    zo.z = f2bf(a2 + bf2f(xv.z)); zo.w = f2bf(a3 + bf2f(xv.w));
    z4[(size_t)node * 32 + lane] = zo;
}

// ---------------- fused MLP: out = (relu(z@W1+b1))@W2 + b2, + BN stats ----------------
// h1 never leaves LDS: per-wave 4KB tile buffer, XOR-swizzled (byte ^= (row&7)<<4)
// so 16-lane row-sliced ds_read_b128 is conflict-free. Per-wave DS ops are in-order
// -> no barriers inside the loop (pattern validated in R4).
__global__ __launch_bounds__(256, 2)
void fused_mlp(const ushort* __restrict__ Z, const ushort* __restrict__ wp,
               const float* __restrict__ b1, const float* __restrict__ b2,
               float* __restrict__ out, float* __restrict__ stats, int nTiles) {
    __shared__ ushort W1s[16384];     // 32 KB
    __shared__ ushort W2s[16384];     // 32 KB
    __shared__ ushort tileb[4][2048]; // 4 KB per wave
    {
        const float4* g = (const float4*)wp;
        float4* l1 = (float4*)W1s;
        float4* l2 = (float4*)W2s;
        for (int i = threadIdx.x; i < 2048; i += 256) { l1[i] = g[i]; l2[i] = g[2048 + i]; }
    }
    __syncthreads();

    int wave = threadIdx.x >> 6, lane = threadIdx.x & 63;
    int rsel = lane & 15;      // A-row / C-col selector
    int csel = lane >> 4;      // k-chunk / C-row-group selector
    char* tb = (char*)tileb[wave];

    float b1v[8], b2v[8];
    #pragma unroll
    for (int nf = 0; nf < 8; ++nf) { b1v[nf] = b1[nf * 16 + rsel]; b2v[nf] = b2[nf * 16 + rsel]; }
    float ssum[8], ssq[8];
    #pragma unroll
    for (int nf = 0; nf < 8; ++nf) { ssum[nf] = 0.f; ssq[nf] = 0.f; }

    for (int tile = blockIdx.x * 4 + wave; tile < nTiles; tile += gridDim.x * 4) {
        int row0 = tile * 16;
        const ushort* aP = Z + (size_t)(row0 + rsel) * D + csel * 8;
        // ---- GEMM1: acc = z @ W1 (A straight from global) ----
        f32x4 acc[8];
        #pragma unroll
        for (int nf = 0; nf < 8; ++nf) acc[nf] = (f32x4){0.f, 0.f, 0.f, 0.f};
        #pragma unroll
        for (int ks = 0; ks < 4; ++ks) {
            s16x8 a = *(const s16x8*)(aP + ks * 32);
            #pragma unroll
            for (int nf = 0; nf < 8; ++nf) {
                s16x8 b = *(const s16x8*)(&W1s[((ks * 8 + nf) * 64 + lane) * 8]);
                acc[nf] = __builtin_amdgcn_mfma_f32_16x16x32_bf16(a, b, acc[nf], 0, 0, 0);
            }
        }
        // ---- h1 = relu(acc + b1) -> per-wave LDS (swizzled) ----
        #pragma unroll
        for (int nf = 0; nf < 8; ++nf) {
            int col2 = (nf * 16 + rsel) * 2;
            #pragma unroll
            for (int r4 = 0; r4 < 4; ++r4) {
                int rr = csel * 4 + r4;
                float v = fmaxf(acc[nf][r4] + b1v[nf], 0.f);
                *(ushort*)(tb + rr * 256 + (col2 ^ ((rr & 7) << 4))) = f2bf(v);
            }
        }
        // ---- GEMM2: acc = h1 @ W2 (A from LDS, swizzled read) ----
        #pragma unroll
        for (int nf = 0; nf < 8; ++nf) acc[nf] = (f32x4){0.f, 0.f, 0.f, 0.f};
        #pragma unroll
        for (int ks = 0; ks < 4; ++ks) {
            s16x8 a = *(const s16x8*)(tb + rsel * 256 + ((ks * 64 + csel * 16) ^ ((rsel & 7) << 4)));
            #pragma unroll
            for (int nf = 0; nf < 8; ++nf) {
                s16x8 b = *(const s16x8*)(&W2s[((ks * 8 + nf) * 64 + lane) * 8]);
                acc[nf] = __builtin_amdgcn_mfma_f32_16x16x32_bf16(a, b, acc[nf], 0, 0, 0);
            }
        }
        // ---- out = acc + b2 (fp32), stats in regs ----
        #pragma unroll
        for (int nf = 0; nf < 8; ++nf) {
            int col = nf * 16 + rsel;
            #pragma unroll
            for (int r4 = 0; r4 < 4; ++r4) {
                float v = acc[nf][r4] + b2v[nf];
                out[(size_t)(row0 + csel * 4 + r4) * D + col] = v;
                ssum[nf] += v; ssq[nf] += v * v;
            }
        }
    }
    // ---- flush stats ----
    #pragma unroll
    for (int nf = 0; nf < 8; ++nf) {
        float s = ssum[nf], q = ssq[nf];
        s += __shfl_xor(s, 16); s += __shfl_xor(s, 32);
        q += __shfl_xor(q, 16); q += __shfl_xor(q, 32);
        if (csel == 0) {
            atomicAdd(&stats[nf * 16 + rsel], s);
            atomicAdd(&stats[128 + nf * 16 + rsel], q);
        }
    }
}

// ---------------- BN normalize + residual ----------------
__global__ void bn_final(float4* __restrict__ out4, const float4* __restrict__ x4,
                         const float* __restrict__ stats, const float* __restrict__ gamma,
                         const float* __restrict__ beta, int n4, float invN) {
    int i = blockIdx.x * blockDim.x + threadIdx.x;
    if (i >= n4) return;
    int cc = i & 31;
    const float4* s4 = (const float4*)stats;
    float4 sum = s4[cc], sq = s4[32 + cc];
    float4 g = ((const float4*)gamma)[cc], b = ((const float4*)beta)[cc];
    float4 h = out4[i], xx = x4[i];
    float4 o;
    {
        float m = sum.x * invN, v = sq.x * invN - m * m, iv = rsqrtf(v + 1e-5f);
        o.x = (h.x - m) * iv * g.x + b.x + xx.x;
    }
    {
        float m = sum.y * invN, v = sq.y * invN - m * m, iv = rsqrtf(v + 1e-5f);
        o.y = (h.y - m) * iv * g.y + b.y + xx.y;
    }
    {
        float m = sum.z * invN, v = sq.z * invN - m * m, iv = rsqrtf(v + 1e-5f);
        o.z = (h.z - m) * iv * g.z + b.z + xx.z;
    }
    {
        float m = sum.w * invN, v = sq.w * invN - m * m, iv = rsqrtf(v + 1e-5f);
        o.w = (h.w - m) * iv * g.w + b.w + xx.w;
    }
    out4[i] = o;
}

extern "C" void kernel_launch(void* const* d_in, const int* in_sizes, int n_in,
                              void* d_out, int out_size, void* d_ws, size_t ws_size,
                              hipStream_t stream) {
    const float* x     = (const float*)d_in[0];
    const int*   ei    = (const int*)d_in[1];
    const float* W1    = (const float*)d_in[2];
    const float* b1    = (const float*)d_in[3];
    const float* W2    = (const float*)d_in[4];
    const float* b2    = (const float*)d_in[5];
    const float* gamma = (const float*)d_in[6];
    const float* beta  = (const float*)d_in[7];
    float* out = (float*)d_out;

    int N = in_sizes[0] / D;   // 50000
    int E = in_sizes[1] / 2;   // 600000
    const int* src = ei;
    const int* dst = ei + E;

    size_t NB = (size_t)N * D;
    ushort* xh   = (ushort*)d_ws;          // NB ushorts
    ushort* z    = xh + NB;                // NB ushorts
    ushort* wp   = z + NB;                 // 2*16384
    float*  stats = (float*)(wp + 32768);  // 256 floats (16B aligned)
    int*    cnt  = (int*)(stats + 256);    // N
    int*    tot  = cnt + N;                // 1
    int*    startA = tot + 1;              // N
    int*    cur  = startA + N;             // N
    int*    bucket = cur + N;              // E

    hipMemsetAsync(stats, 0, (size_t)(256 + N + 1) * sizeof(int), stream);

    const int B = 256;
    int n4 = (int)(NB / 4);
    prep_kernel<<<2048, B, 0, stream>>>((const float4*)x, (ushort4*)xh, n4,
                                        dst, cnt, E, W1, W2, wp);
    alloc_kernel<<<(N + B - 1) / B, B, 0, stream>>>(cnt, startA, cur, tot, N);
    fill_kernel<<<(E + B - 1) / B, B, 0, stream>>>(src, dst, cur, bucket, E);
    gather_kernel<<<(N + 7) / 8, B, 0, stream>>>((const ushort4*)xh, startA, cnt, bucket,
                                                 (ushort4*)z, N);
    int nTiles = (N + 15) / 16;   // 3125
    fused_mlp<<<391, B, 0, stream>>>(z, wp, b1, b2, out, stats, nTiles);
    bn_final<<<(n4 + B - 1) / B, B, 0, stream>>>((float4*)out, (const float4*)x, stats,
                                                 gamma, beta, n4, 1.0f / (float)N);
}